// Round 11
// baseline (61.258 us; speedup 1.0000x reference)
//
#include <hip/hip_runtime.h>

typedef float f32x4 __attribute__((ext_vector_type(4)));

// B=4096 rows, NPTS=4097 points, M=4096 outputs per row.
constexpr int NPTS = 4097;
constexpr int M    = 4096;
constexpr int TPB  = 256;   // 4 waves
constexpr int NW   = TPB / 64;
constexpr int NJ   = 4;     // 4 groups of 4 elements per thread; NJ*TPB*4 == M
// thread owns elements e(j) = j*1024 + tid*4 .. +3 (lane-contiguous)

// 4-element trapezoid scan from two aligned f32x4 loads; S = row misalignment
// (compile-time -> pure register selects, no scratch).
template<int S>
__device__ __forceinline__ void scan4(const f32x4 a, const f32x4 c,
                                      const f32x4 tq, float tn,
                                      float (&xsj)[4], float (&zlj)[4], float& gsj)
{
    const float m[8] = {a.x, a.y, a.z, a.w, c.x, c.y, c.z, c.w};
    const float x0 = m[S+0], x1 = m[S+1], x2 = m[S+2], x3 = m[S+3], x4 = m[S+4];
    const float i0 = (0.5f * (tq.y - tq.x)) * (x0 + x1);
    const float i1 = (0.5f * (tq.z - tq.y)) * (x1 + x2);
    const float i2 = (0.5f * (tq.w - tq.z)) * (x2 + x3);
    const float i3 = (0.5f * (tn   - tq.w)) * (x3 + x4);
    zlj[0] = i0;
    zlj[1] = i0 + i1;
    zlj[2] = zlj[1] + i2;
    zlj[3] = zlj[2] + i3;
    gsj = zlj[3];
    xsj[0] = x1; xsj[1] = x2; xsj[2] = x3; xsj[3] = x4;
}

// Shared front half: coalesced loads, local scans, 4 wave scans, block fixup.
// On return: zl[j][i] = z values, xs = x_sl, all in registers.
template<int S>
__device__ __forceinline__ void front(const float* __restrict__ x,
                                      const float* __restrict__ t,
                                      float ny, int b,
                                      float (&xs)[NJ][4], float (&zl)[NJ][4],
                                      float (*wt)[NJ])
{
    const int tid  = threadIdx.x;
    const int lane = tid & 63;
    const int wid  = tid >> 6;
    // x row base = b*4097 floats; b*4097 ≡ b (mod 4) -> (xrow - S), S=b&3, is
    // 16B-aligned. Row b=4095 (S=3) reads end exactly at x's last element;
    // S<3 rows over-read <=3 floats into the next row (in bounds).
    const float* __restrict__ xal = x + (size_t)b * NPTS - S;

    float gs[NJ];
#pragma unroll
    for (int j = 0; j < NJ; ++j) {
        const int e = j * 1024 + tid * 4;
        const f32x4 a4 = *(const f32x4*)(xal + e);
        const f32x4 c4 = *(const f32x4*)(xal + e + 4);
        const f32x4 tq = *(const f32x4*)(t + e);   // aligned, L2-hot
        const float tn = t[e + 4];                 // coalesced scalar, L2-hot
        scan4<S>(a4, c4, tq, tn, xs[j], zl[j], gs[j]);
    }

    // 4 simultaneous wave inclusive scans of group sums
    float sc[NJ];
#pragma unroll
    for (int c = 0; c < NJ; ++c) sc[c] = gs[c];
#pragma unroll
    for (int d = 1; d < 64; d <<= 1) {
#pragma unroll
        for (int c = 0; c < NJ; ++c) {
            float u = __shfl_up(sc[c], d, 64);
            if (lane >= d) sc[c] += u;
        }
    }
    if (lane == 63) {
#pragma unroll
        for (int c = 0; c < NJ; ++c) wt[wid][c] = sc[c];
    }
    __syncthreads();

    float woff[NJ] = {}, Tt[NJ] = {};
#pragma unroll
    for (int w = 0; w < NW; ++w) {
#pragma unroll
        for (int c = 0; c < NJ; ++c) {
            const float v = wt[w][c];
            Tt[c] += v;
            if (w < wid) woff[c] += v;
        }
    }
    // exclusive prefix per group; z = zb + local scan
    float jacc = 0.f;
#pragma unroll
    for (int j = 0; j < NJ; ++j) {
        const float zb = ny + jacc + woff[j] + (sc[j] - gs[j]);
        jacc += Tt[j];
#pragma unroll
        for (int i = 0; i < 4; ++i) zl[j][i] = zb + zl[j][i];
    }
}

// ---------------- K1: per-row coeffs + r2 (tiny writes) ----------------
template<int S, bool RHALF>
__device__ __forceinline__ void body1(const float* __restrict__ x,
                                      const float* __restrict__ t,
                                      float r, float ny,
                                      float* __restrict__ out, int b, int B)
{
    __shared__ float wt[NW][NJ];
    __shared__ float gram[NW][6];
    const int tid  = threadIdx.x;
    const int lane = tid & 63;
    const int wid  = tid >> 6;

    float xs[NJ][4], zl[NJ][4];
    front<S>(x, t, ny, b, xs, zl, wt);

    // Gram/projection sums in f32 (group-pairwise), + Sxx for r2 identity
    float s0 = 0, s1 = 0, s2 = 0, s3 = 0, s4 = 0, s5 = 0;
#pragma unroll
    for (int j = 0; j < NJ; ++j) {
        float pzz = 0, pzw = 0, pww = 0, pxz = 0, pxw = 0, pxx = 0;
#pragma unroll
        for (int i = 0; i < 4; ++i) {
            const float z  = zl[j][i];
            const float w  = RHALF ? sqrtf(z) : powf(z, r);
            const float xv = xs[j][i];
            pzz = fmaf(z,  z,  pzz);
            pzw = fmaf(z,  w,  pzw);
            pww = fmaf(w,  w,  pww);
            pxz = fmaf(xv, z,  pxz);
            pxw = fmaf(xv, w,  pxw);
            pxx = fmaf(xv, xv, pxx);
        }
        s0 += pzz; s1 += pzw; s2 += pww; s3 += pxz; s4 += pxw; s5 += pxx;
    }
#pragma unroll
    for (int d = 32; d > 0; d >>= 1) {
        s0 += __shfl_down(s0, d, 64);
        s1 += __shfl_down(s1, d, 64);
        s2 += __shfl_down(s2, d, 64);
        s3 += __shfl_down(s3, d, 64);
        s4 += __shfl_down(s4, d, 64);
        s5 += __shfl_down(s5, d, 64);
    }
    if (lane == 0) {
        gram[wid][0] = s0; gram[wid][1] = s1; gram[wid][2] = s2;
        gram[wid][3] = s3; gram[wid][4] = s4; gram[wid][5] = s5;
    }
    __syncthreads();

    if (tid == 0) {
        double a0 = 0, a1 = 0, a2 = 0, a3 = 0, a4 = 0, a5 = 0;
#pragma unroll
        for (int w = 0; w < NW; ++w) {
            a0 += gram[w][0]; a1 += gram[w][1]; a2 += gram[w][2];
            a3 += gram[w][3]; a4 += gram[w][4]; a5 += gram[w][5];
        }
        const double det = a0 * a2 - a1 * a1;
        const double inv = 1.0 / det;
        const double c0d = (a3 * a2 - a4 * a1) * inv;
        const double c1d = (a4 * a0 - a3 * a1) * inv;
        out[(size_t)b * 2 + 0] = (float)c0d;
        out[(size_t)b * 2 + 1] = (float)c1d;
        // r2 via LS identity: Sxx - c0*Sxz - c1*Sxw (exact at optimum)
        out[(size_t)B * 2 + 2 * (size_t)B * M + b] =
            (float)(a5 - c0d * a3 - c1d * a4);
    }
}

__global__ __launch_bounds__(TPB)
void k_coeff(const float* __restrict__ x, const float* __restrict__ t,
             const float* __restrict__ params, float* __restrict__ out, int B)
{
    const float r  = params[0];
    const float ny = params[1];
    const int  b   = blockIdx.x;
    if (r == 0.5f) {
        switch (b & 3) {
        case 0:  body1<0, true>(x, t, r, ny, out, b, B); break;
        case 1:  body1<1, true>(x, t, r, ny, out, b, B); break;
        case 2:  body1<2, true>(x, t, r, ny, out, b, B); break;
        default: body1<3, true>(x, t, r, ny, out, b, B); break;
        }
    } else {
        switch (b & 3) {
        case 0:  body1<0, false>(x, t, r, ny, out, b, B); break;
        case 1:  body1<1, false>(x, t, r, ny, out, b, B); break;
        case 2:  body1<2, false>(x, t, r, ny, out, b, B); break;
        default: body1<3, false>(x, t, r, ny, out, b, B); break;
        }
    }
}

// ---------------- K2: emit x_hat/res (one barrier, stream writes) ----------
template<int S, bool RHALF>
__device__ __forceinline__ void body2(const float* __restrict__ x,
                                      const float* __restrict__ t,
                                      float r, float ny,
                                      float* __restrict__ out, int b, int B)
{
    __shared__ float wt[NW][NJ];
    const int tid = threadIdx.x;

    // per-row coeffs written by K1 (stream-ordered earlier in this call)
    const float c0 = out[(size_t)b * 2 + 0];
    const float c1 = out[(size_t)b * 2 + 1];

    float xs[NJ][4], zl[NJ][4];
    front<S>(x, t, ny, b, xs, zl, wt);

    float* __restrict__ xhat = out + (size_t)B * 2 + (size_t)b * M;
    float* __restrict__ res  = xhat + (size_t)B * M;

#pragma unroll
    for (int j = 0; j < NJ; ++j) {
        const int e = j * 1024 + tid * 4;
        f32x4 hv, rv;
#pragma unroll
        for (int i = 0; i < 4; ++i) {
            const float z = zl[j][i];
            const float w = RHALF ? sqrtf(z) : powf(z, r);
            const float h = c0 * z + c1 * w;
            hv[i] = h;
            rv[i] = xs[j][i] - h;
        }
        *(f32x4*)(xhat + e) = hv;
        *(f32x4*)(res  + e) = rv;
    }
}

__global__ __launch_bounds__(TPB)
void k_emit(const float* __restrict__ x, const float* __restrict__ t,
            const float* __restrict__ params, float* __restrict__ out, int B)
{
    const float r  = params[0];
    const float ny = params[1];
    const int  b   = blockIdx.x;
    if (r == 0.5f) {
        switch (b & 3) {
        case 0:  body2<0, true>(x, t, r, ny, out, b, B); break;
        case 1:  body2<1, true>(x, t, r, ny, out, b, B); break;
        case 2:  body2<2, true>(x, t, r, ny, out, b, B); break;
        default: body2<3, true>(x, t, r, ny, out, b, B); break;
        }
    } else {
        switch (b & 3) {
        case 0:  body2<0, false>(x, t, r, ny, out, b, B); break;
        case 1:  body2<1, false>(x, t, r, ny, out, b, B); break;
        case 2:  body2<2, false>(x, t, r, ny, out, b, B); break;
        default: body2<3, false>(x, t, r, ny, out, b, B); break;
        }
    }
}

extern "C" void kernel_launch(void* const* d_in, const int* in_sizes, int n_in,
                              void* d_out, int out_size, void* d_ws, size_t ws_size,
                              hipStream_t stream) {
    const float* x = (const float*)d_in[0];
    const float* t = (const float*)d_in[1];
    const float* p = (const float*)d_in[2];
    float* out     = (float*)d_out;
    const int B    = in_sizes[0] / NPTS;   // 4096

    k_coeff<<<dim3(B), dim3(TPB), 0, stream>>>(x, t, p, out, B);
    k_emit <<<dim3(B), dim3(TPB), 0, stream>>>(x, t, p, out, B);
}

// Round 12
// 44.503 us; speedup vs baseline: 1.3765x; 1.3765x over previous
//
#include <hip/hip_runtime.h>

typedef float f32x4 __attribute__((ext_vector_type(4)));

// B=4096 rows, NPTS=4097 points, M=4096 outputs per row.
constexpr int NPTS = 4097;
constexpr int M    = 4096;
constexpr int TPB  = 256;   // 4 waves
constexpr int NW   = TPB / 64;
constexpr int NJ   = 4;     // 4 groups of 4 elements per thread; NJ*TPB*4 == M
constexpr int RPB  = 4;     // rows per block, processed sequentially (pipelined)
// thread owns elements e(j) = j*1024 + tid*4 .. +3 (lane-contiguous)

struct Lds {
    float wt[2][NW][NJ];    // double-buffered by row parity
    float gram[2][NW][6];
};

// 4-element trapezoid scan; S = row misalignment (compile-time selects).
template<int S>
__device__ __forceinline__ void scan4(const f32x4 a, const f32x4 c,
                                      const float (&dj)[4],
                                      float (&xsj)[4], float (&zlj)[4],
                                      float& gsj)
{
    const float m[8] = {a.x, a.y, a.z, a.w, c.x, c.y, c.z, c.w};
    const float x0 = m[S+0], x1 = m[S+1], x2 = m[S+2], x3 = m[S+3], x4 = m[S+4];
    const float i0 = dj[0] * (x0 + x1);
    const float i1 = dj[1] * (x1 + x2);
    const float i2 = dj[2] * (x2 + x3);
    const float i3 = dj[3] * (x3 + x4);
    zlj[0] = i0;
    zlj[1] = i0 + i1;
    zlj[2] = zlj[1] + i2;
    zlj[3] = zlj[2] + i3;
    gsj = zlj[3];
    xsj[0] = x1; xsj[1] = x2; xsj[2] = x3; xsj[3] = x4;
}

// One full row: prefetch next row's x, then scan/fixup/gram/solve/store.
// Row b = b0+R has misalignment S = b&3 = R (b0 = 4*blockIdx ≡ 0 mod 4).
// Row pointer: x + b*NPTS - R = xbase + R*4096, xbase = x + bid*4*NPTS.
template<int R, bool RHALF>
__device__ __forceinline__ void step(
    const float* __restrict__ xbase, const float (&d)[NJ][4],
    float r, float ny, float* __restrict__ out,
    int b0, int B, Lds& L,
    f32x4 (&ca)[NJ], f32x4 (&cc)[NJ],    // current row raw loads (ready)
    f32x4 (&na)[NJ], f32x4 (&nc)[NJ])    // next row buffers (filled here)
{
    const int tid  = threadIdx.x;
    const int lane = tid & 63;
    const int wid  = tid >> 6;
    const int b    = b0 + R;
    constexpr int BUF = R & 1;

    // ---- prefetch next row's x (independent loads; hoisted above waits) ----
    if (R < RPB - 1) {
        const float* __restrict__ nx = xbase + (R + 1) * 4096;
#pragma unroll
        for (int j = 0; j < NJ; ++j) {
            const int e = j * 1024 + tid * 4;
            na[j] = *(const f32x4*)(nx + e);
            nc[j] = *(const f32x4*)(nx + e + 4);
        }
    }

    // ---- local scans ----
    float xs[NJ][4], zl[NJ][4], gs[NJ];
#pragma unroll
    for (int j = 0; j < NJ; ++j)
        scan4<R>(ca[j], cc[j], d[j], xs[j], zl[j], gs[j]);

    // ---- 4 simultaneous wave inclusive scans of group sums ----
    float sc[NJ];
#pragma unroll
    for (int c = 0; c < NJ; ++c) sc[c] = gs[c];
#pragma unroll
    for (int dd = 1; dd < 64; dd <<= 1) {
#pragma unroll
        for (int c = 0; c < NJ; ++c) {
            float u = __shfl_up(sc[c], dd, 64);
            if (lane >= dd) sc[c] += u;
        }
    }
    if (lane == 63) {
#pragma unroll
        for (int c = 0; c < NJ; ++c) L.wt[BUF][wid][c] = sc[c];
    }
    __syncthreads();

    float woff[NJ] = {}, Tt[NJ] = {};
#pragma unroll
    for (int w = 0; w < NW; ++w) {
#pragma unroll
        for (int c = 0; c < NJ; ++c) {
            const float v = L.wt[BUF][w][c];
            Tt[c] += v;
            if (w < wid) woff[c] += v;
        }
    }
    {
        float jacc = 0.f;
#pragma unroll
        for (int j = 0; j < NJ; ++j) {
            const float zb = ny + jacc + woff[j] + (sc[j] - gs[j]);
            jacc += Tt[j];
#pragma unroll
            for (int i = 0; i < 4; ++i) zl[j][i] = zb + zl[j][i];
        }
    }

    // ---- Gram/projection sums in f32 (group-pairwise), + Sxx ----
    float s0 = 0, s1 = 0, s2 = 0, s3 = 0, s4 = 0, s5 = 0;
#pragma unroll
    for (int j = 0; j < NJ; ++j) {
        float pzz = 0, pzw = 0, pww = 0, pxz = 0, pxw = 0, pxx = 0;
#pragma unroll
        for (int i = 0; i < 4; ++i) {
            const float z  = zl[j][i];
            const float w  = RHALF ? sqrtf(z) : powf(z, r);
            const float xv = xs[j][i];
            pzz = fmaf(z,  z,  pzz);
            pzw = fmaf(z,  w,  pzw);
            pww = fmaf(w,  w,  pww);
            pxz = fmaf(xv, z,  pxz);
            pxw = fmaf(xv, w,  pxw);
            pxx = fmaf(xv, xv, pxx);
        }
        s0 += pzz; s1 += pzw; s2 += pww; s3 += pxz; s4 += pxw; s5 += pxx;
    }
#pragma unroll
    for (int dd = 32; dd > 0; dd >>= 1) {
        s0 += __shfl_down(s0, dd, 64);
        s1 += __shfl_down(s1, dd, 64);
        s2 += __shfl_down(s2, dd, 64);
        s3 += __shfl_down(s3, dd, 64);
        s4 += __shfl_down(s4, dd, 64);
        s5 += __shfl_down(s5, dd, 64);
    }
    if (lane == 0) {
        L.gram[BUF][wid][0] = s0; L.gram[BUF][wid][1] = s1;
        L.gram[BUF][wid][2] = s2; L.gram[BUF][wid][3] = s3;
        L.gram[BUF][wid][4] = s4; L.gram[BUF][wid][5] = s5;
    }
    __syncthreads();

    // ---- 2x2 solve (f64, redundant per-thread from LDS broadcast) ----
    double a0 = 0, a1 = 0, a2 = 0, a3 = 0, a4 = 0, a5 = 0;
#pragma unroll
    for (int w = 0; w < NW; ++w) {
        a0 += L.gram[BUF][w][0]; a1 += L.gram[BUF][w][1];
        a2 += L.gram[BUF][w][2]; a3 += L.gram[BUF][w][3];
        a4 += L.gram[BUF][w][4]; a5 += L.gram[BUF][w][5];
    }
    const double det = a0 * a2 - a1 * a1;
    const double inv = 1.0 / det;
    const double c0d = (a3 * a2 - a4 * a1) * inv;
    const double c1d = (a4 * a0 - a3 * a1) * inv;
    const float c0 = (float)c0d;
    const float c1 = (float)c1d;
    if (tid == 0) {
        out[(size_t)b * 2 + 0] = c0;
        out[(size_t)b * 2 + 1] = c1;
        // r2 via LS identity: Sxx - c0*Sxz - c1*Sxw (exact at the optimum)
        out[(size_t)B * 2 + 2 * (size_t)B * M + b] =
            (float)(a5 - c0d * a3 - c1d * a4);
    }

    // ---- x_hat, res (coalesced f32x4 stores) ----
    float* __restrict__ xhat = out + (size_t)B * 2 + (size_t)b * M;
    float* __restrict__ res  = xhat + (size_t)B * M;
#pragma unroll
    for (int j = 0; j < NJ; ++j) {
        const int e = j * 1024 + tid * 4;
        f32x4 hv, rv;
#pragma unroll
        for (int i = 0; i < 4; ++i) {
            const float z = zl[j][i];
            const float w = RHALF ? sqrtf(z) : powf(z, r);
            const float h = c0 * z + c1 * w;
            hv[i] = h;
            rv[i] = xs[j][i] - h;
        }
        *(f32x4*)(xhat + e) = hv;
        *(f32x4*)(res  + e) = rv;
    }
}

template<bool RHALF>
__device__ __forceinline__ void run(const float* __restrict__ x,
                                    const float* __restrict__ t,
                                    float r, float ny,
                                    float* __restrict__ out, int B, Lds& L)
{
    const int tid = threadIdx.x;
    const int bid = blockIdx.x;
    const int b0  = bid * RPB;
    const float* __restrict__ xbase = x + (size_t)bid * (RPB * NPTS);
    // row R pointer = xbase + R*4096 (16B-aligned); S=R compile-time.
    // Last block, R=3: reads end exactly at x's last element; other rows
    // over-read <=3 floats into the next row (in bounds).

    // t-derived trapezoid half-widths, computed ONCE, reused for all 4 rows
    float d[NJ][4];
#pragma unroll
    for (int j = 0; j < NJ; ++j) {
        const int e = j * 1024 + tid * 4;
        const f32x4 tq = *(const f32x4*)(t + e);
        const float tn = t[e + 4];
        d[j][0] = 0.5f * (tq.y - tq.x);
        d[j][1] = 0.5f * (tq.z - tq.y);
        d[j][2] = 0.5f * (tq.w - tq.z);
        d[j][3] = 0.5f * (tn   - tq.w);
    }

    f32x4 pa[NJ], pc[NJ], qa[NJ], qc[NJ];
#pragma unroll
    for (int j = 0; j < NJ; ++j) {
        const int e = j * 1024 + tid * 4;
        pa[j] = *(const f32x4*)(xbase + e);
        pc[j] = *(const f32x4*)(xbase + e + 4);
    }

    step<0, RHALF>(xbase, d, r, ny, out, b0, B, L, pa, pc, qa, qc);
    step<1, RHALF>(xbase, d, r, ny, out, b0, B, L, qa, qc, pa, pc);
    step<2, RHALF>(xbase, d, r, ny, out, b0, B, L, pa, pc, qa, qc);
    step<3, RHALF>(xbase, d, r, ny, out, b0, B, L, qa, qc, pa, pc);
}

__global__ __launch_bounds__(TPB)
void vp_kernel(const float* __restrict__ x, const float* __restrict__ t,
               const float* __restrict__ params, float* __restrict__ out, int B)
{
    __shared__ Lds L;
    const float r  = params[0];
    const float ny = params[1];
    if (r == 0.5f) run<true >(x, t, r, ny, out, B, L);
    else           run<false>(x, t, r, ny, out, B, L);
}

extern "C" void kernel_launch(void* const* d_in, const int* in_sizes, int n_in,
                              void* d_out, int out_size, void* d_ws, size_t ws_size,
                              hipStream_t stream) {
    const float* x = (const float*)d_in[0];
    const float* t = (const float*)d_in[1];
    const float* p = (const float*)d_in[2];
    float* out     = (float*)d_out;
    const int B    = in_sizes[0] / NPTS;   // 4096

    vp_kernel<<<dim3(B / RPB), dim3(TPB), 0, stream>>>(x, t, p, out, B);
}